// Round 1
// 497.925 us; speedup vs baseline: 1.0510x; 1.0510x over previous
//
#include <hip/hip_runtime.h>
#include <hip/hip_bf16.h>

typedef __bf16 bf16_t;
typedef __bf16 bf16x8 __attribute__((ext_vector_type(8)));
typedef __bf16 bf16x4 __attribute__((ext_vector_type(4)));
typedef float f32x4 __attribute__((ext_vector_type(4)));

#define B_ 16
#define T_ 128
#define H_ 512
#define L_ 2
#define V_ 32000
#define G_ 2048   /* 4*H */
#define M_ 2048   /* B*T */

#define BM 128
#define BN 128
#define BK 32

__device__ __forceinline__ float sigf(float x) { return 1.f / (1.f + __expf(-x)); }
__device__ __forceinline__ float tanhf_(float x) { return 2.f / (1.f + __expf(-2.f * x)) - 1.f; }

// Gate-interleaved column permutation for the LSTM-gate GEMMs:
//   permuted col c in [0,2048): gate = (c>>4)&3, h = ((c>>6)<<4) | (c&15)
//   original gate row r = gate*H_ + h
// Within each 64-col group, cols {0,16,32,48}+r16 are gates i,f,g,o of ONE
// hidden unit h — which is exactly the set of columns one lane's acc[mi][0..3]
// holds in the 16x16x32 MFMA fragment layout (ni stride = 16). So the LSTM
// pointwise can run entirely in the GEMM epilogue registers.

// ---------------- mega prep kernel: 4 independent jobs by block range --------
// [0,256)        hproj  : biasall[l][b][c_perm] = b_ih+b_hh+h0@W_hh  (65536 thr)
// [256,2304)     wih    : W_ih fp32 -> bf16, gate-permuted rows      (524288 thr)
// [2304,3328)    embed  : x = relu(emb[tokens]) -> bf16              (262144 thr)
// [3328,19328)   wout   : W_out fp32 -> bf16                         (4096000 thr)
__global__ __launch_bounds__(256) void prep(const float* __restrict__ emb,
                                            const int* __restrict__ target,
                                            const float* __restrict__ enc_h,
                                            const float* __restrict__ W_ih,
                                            const float* __restrict__ W_hh,
                                            const float* __restrict__ b_ih,
                                            const float* __restrict__ b_hh,
                                            const float* __restrict__ W_out,
                                            bf16_t* __restrict__ x,
                                            bf16_t* __restrict__ wih_b,
                                            bf16_t* __restrict__ wout_b,
                                            float* __restrict__ biasall) {
    const int blk = blockIdx.x;
    const int tid = threadIdx.x;
    if (blk < 256) {
        // ---- hproj (gate-permuted bias table) ----
        int idx = blk * 256 + tid;             // L_*G_*B_
        int b = idx & 15;
        int c = (idx >> 4) & (G_ - 1);
        int l = idx >> 15;
        int gate = (c >> 4) & 3;
        int h = ((c >> 6) << 4) | (c & 15);
        int r = gate * H_ + h;                 // original gate row
        const float* hrow = enc_h + ((size_t)l * B_ + b) * H_;
        const float* wrow = W_hh + ((size_t)l * G_ + r) * H_;
        float acc = b_ih[l * G_ + r] + b_hh[l * G_ + r];
        #pragma unroll 4
        for (int k = 0; k < H_; k += 4) {
            float4 hv = *(const float4*)(hrow + k);
            float4 wv = *(const float4*)(wrow + k);
            acc += hv.x * wv.x + hv.y * wv.y + hv.z * wv.z + hv.w * wv.w;
        }
        biasall[((size_t)l * B_ + b) * G_ + c] = acc;
    } else if (blk < 2304) {
        // ---- W_ih convert + gate-permute rows ----
        int idx = (blk - 256) * 256 + tid;     // L_*G_*(H_/4)
        int k4 = idx & 127;
        int c  = (idx >> 7) & (G_ - 1);
        int l  = idx >> 18;
        int gate = (c >> 4) & 3;
        int h = ((c >> 6) << 4) | (c & 15);
        int r = gate * H_ + h;
        float4 v = *(const float4*)(W_ih + ((size_t)l * G_ + r) * H_ + k4 * 4);
        bf16x4 o;
        o[0] = (bf16_t)v.x; o[1] = (bf16_t)v.y; o[2] = (bf16_t)v.z; o[3] = (bf16_t)v.w;
        *(bf16x4*)(wih_b + ((size_t)l * G_ + c) * H_ + k4 * 4) = o;
    } else if (blk < 3328) {
        // ---- embedding gather + relu -> bf16 ----
        int idx = (blk - 2304) * 256 + tid;    // M_*(H_/4)
        int m  = idx >> 7;
        int h4 = (idx & 127) << 2;
        int b = m >> 7, t = m & 127;
        int tok = (t == 0) ? 1 : target[b * T_ + t - 1];
        float4 v = *(const float4*)(emb + (size_t)tok * H_ + h4);
        bf16x4 o;
        o[0] = (bf16_t)fmaxf(v.x, 0.f);
        o[1] = (bf16_t)fmaxf(v.y, 0.f);
        o[2] = (bf16_t)fmaxf(v.z, 0.f);
        o[3] = (bf16_t)fmaxf(v.w, 0.f);
        *(bf16x4*)(x + (size_t)m * H_ + h4) = o;
    } else {
        // ---- W_out convert ----
        int idx = (blk - 3328) * 256 + tid;    // V_*H_/4
        float4 v = ((const float4*)W_out)[idx];
        bf16x4 o;
        o[0] = (bf16_t)v.x; o[1] = (bf16_t)v.y; o[2] = (bf16_t)v.z; o[3] = (bf16_t)v.w;
        ((bf16x4*)wout_b)[idx] = o;
    }
}

// ---------------- bf16 GEMM:  C(MxN) = A(MxK) @ B(NxK)^T  -------------------
// mode 0: logits epilogue, C[row*N+col] = acc + bias[col]  (nontemporal store)
// mode 1: fused LSTM epilogue (gate-permuted B/bias), writes xout bf16 and
//         out_h/out_c at t==T_-1; C unused.
// 1D grid, XCD-bijective swizzle: each XCD owns a contiguous chunk of the
// x-fastest linear ordering so a B panel is fetched by ONE XCD's L2 only.
__global__ __launch_bounds__(256) void gemm_bt(const bf16_t* __restrict__ A,
                                               const bf16_t* __restrict__ B,
                                               float* __restrict__ C,
                                               const float* __restrict__ bias,
                                               int M, int N, int K, int mode,
                                               const float* __restrict__ enc_c,
                                               bf16_t* __restrict__ xout,
                                               float* __restrict__ out_h,
                                               float* __restrict__ out_c,
                                               int l) {
    __shared__ __align__(16) bf16_t As[BM * BK];
    __shared__ __align__(16) bf16_t Bs[BN * BK];

    const int tid  = threadIdx.x;
    const int lane = tid & 63;
    const int wave = tid >> 6;
    const int wm = wave >> 1, wn = wave & 1;
    const int quad = lane >> 4;
    const int r16  = lane & 15;

    // XCD-bijective remap (gridDim.x divisible by 8 here: 4000 or 256)
    const int nwg = gridDim.x;
    const int q = nwg >> 3;
    const int wg = (blockIdx.x & 7) * q + (blockIdx.x >> 3);
    const int bx = wg & 15;          // M/BM == 16 for all our shapes
    const int by = wg >> 4;
    const int tileM = bx * BM;
    const int tileN = by * BN;

    const int srow = lane >> 2;
    const int scol = (lane & 3) * 8;

    f32x4 acc[4][4];
    #pragma unroll
    for (int i = 0; i < 4; i++)
        #pragma unroll
        for (int j = 0; j < 4; j++) acc[i][j] = (f32x4){0.f, 0.f, 0.f, 0.f};

    const int nk = K / BK;
    for (int kt = 0; kt < nk; ++kt) {
        const int k0 = kt * BK;
        #pragma unroll
        for (int j = 0; j < 2; ++j) {
            const int r0 = j * 64 + wave * 16;
            const bf16_t* ga = A + (size_t)(tileM + r0 + srow) * K + k0 + scol;
            const bf16_t* gb = B + (size_t)(tileN + r0 + srow) * K + k0 + scol;
            __builtin_amdgcn_global_load_lds(
                (const __attribute__((address_space(1))) void*)ga,
                (__attribute__((address_space(3))) void*)(As + r0 * BK), 16, 0, 0);
            __builtin_amdgcn_global_load_lds(
                (const __attribute__((address_space(1))) void*)gb,
                (__attribute__((address_space(3))) void*)(Bs + r0 * BK), 16, 0, 0);
        }
        __syncthreads();

        bf16x8 af[4], bfr[4];
        #pragma unroll
        for (int mi = 0; mi < 4; mi++)
            af[mi] = *(const bf16x8*)(As + (wm * 64 + mi * 16 + r16) * BK + quad * 8);
        #pragma unroll
        for (int ni = 0; ni < 4; ni++)
            bfr[ni] = *(const bf16x8*)(Bs + (wn * 64 + ni * 16 + r16) * BK + quad * 8);
        #pragma unroll
        for (int mi = 0; mi < 4; mi++)
            #pragma unroll
            for (int ni = 0; ni < 4; ni++)
                acc[mi][ni] = __builtin_amdgcn_mfma_f32_16x16x32_bf16(
                    af[mi], bfr[ni], acc[mi][ni], 0, 0, 0);
        __syncthreads();
    }

    if (mode == 0) {
        // ---- logits epilogue: bias[col] + nontemporal fp32 store ----
        #pragma unroll
        for (int mi = 0; mi < 4; mi++) {
            #pragma unroll
            for (int ni = 0; ni < 4; ni++) {
                const int col = tileN + wn * 64 + ni * 16 + r16;
                const float bv = bias[col];
                #pragma unroll
                for (int rr = 0; rr < 4; rr++) {
                    const int row = tileM + wm * 64 + mi * 16 + quad * 4 + rr;
                    __builtin_nontemporal_store(acc[mi][ni][rr] + bv,
                                                &C[(size_t)row * N + col]);
                }
            }
        }
    } else {
        // ---- fused LSTM pointwise epilogue ----
        // lane owns hidden unit h = (2*by + wn)*16 + r16; acc[mi][gate] holds
        // the 4 gates (i,f,g,o) for rows tileM + wm*64 + mi*16 + quad*4 + rr.
        const int b = bx;                       // BM == T_, so M-tile == batch
        const float* brow = bias + (size_t)b * G_;
        float bv[4];
        #pragma unroll
        for (int g = 0; g < 4; g++)
            bv[g] = brow[tileN + wn * 64 + g * 16 + r16];
        const int h = (2 * by + wn) * 16 + r16;
        const float c0 = enc_c[((size_t)l * B_ + b) * H_ + h];
        #pragma unroll
        for (int mi = 0; mi < 4; mi++) {
            #pragma unroll
            for (int rr = 0; rr < 4; rr++) {
                const int t = wm * 64 + mi * 16 + quad * 4 + rr;
                const float gi = acc[mi][0][rr] + bv[0];
                const float gf = acc[mi][1][rr] + bv[1];
                const float gg = acc[mi][2][rr] + bv[2];
                const float go = acc[mi][3][rr] + bv[3];
                const float c = sigf(gf) * c0 + sigf(gi) * tanhf_(gg);
                const float hv = sigf(go) * tanhf_(c);
                xout[(size_t)(b * T_ + t) * H_ + h] = (bf16_t)hv;
                if (t == T_ - 1) {
                    out_h[((size_t)l * B_ + b) * H_ + h] = hv;
                    out_c[((size_t)l * B_ + b) * H_ + h] = c;
                }
            }
        }
    }
}

extern "C" void kernel_launch(void* const* d_in, const int* in_sizes, int n_in,
                              void* d_out, int out_size, void* d_ws, size_t ws_size,
                              hipStream_t stream) {
    const float* enc_h  = (const float*)d_in[1];
    const float* enc_c  = (const float*)d_in[2];
    const int*   target = (const int*)d_in[3];
    const float* emb    = (const float*)d_in[4];
    const float* W_ih   = (const float*)d_in[5];
    const float* W_hh   = (const float*)d_in[6];
    const float* b_ih   = (const float*)d_in[7];
    const float* b_hh   = (const float*)d_in[8];
    const float* W_out  = (const float*)d_in[9];
    const float* b_out  = (const float*)d_in[10];
    float* out = (float*)d_out;

    // workspace layout (bytes)
    char* w = (char*)d_ws;
    bf16_t* x       = (bf16_t*)(w);                         // 2048*512*2    = 2 MB
    bf16_t* wih_b   = (bf16_t*)(w + 2097152);               // 2*2048*512*2  = 4 MB
    bf16_t* wout_b  = (bf16_t*)(w + 6291456);               // 32000*512*2   = 32.75 MB
    bf16_t* x2      = (bf16_t*)(w + 39059456);              // 2048*512*2    = 2 MB (ex-gates)
    float*  biasall = (float*)(w + 55836672);               // 2*16*2048*4   = 256 KB

    float* out_h = out + (size_t)M_ * V_;
    float* out_c = out_h + (size_t)L_ * B_ * H_;

    // 1) all prep in one launch (hproj + W_ih perm-cvt + embed + W_out cvt)
    prep<<<19328, 256, 0, stream>>>(emb, target, enc_h, W_ih, W_hh, b_ih, b_hh,
                                    W_out, x, wih_b, wout_b, biasall);

    // 2) two LSTM layers: GEMM with fused pointwise epilogue (x -> x2 -> x)
    gemm_bt<<<(M_ / BM) * (G_ / BN), 256, 0, stream>>>(
        x, wih_b, (float*)x2, biasall, M_, G_, H_, 1,
        enc_c, x2, out_h, out_c, 0);
    gemm_bt<<<(M_ / BM) * (G_ / BN), 256, 0, stream>>>(
        x2, wih_b + (size_t)G_ * H_, (float*)x, biasall + (size_t)B_ * G_,
        M_, G_, H_, 1, enc_c, x, out_h, out_c, 1);

    // 3) logits = x @ W_out^T + b_out
    gemm_bt<<<(M_ / BM) * (V_ / BN), 256, 0, stream>>>(
        x, wout_b, out, b_out, M_, V_, H_, 0,
        nullptr, nullptr, nullptr, nullptr, 0);
}

// Round 2
// 454.391 us; speedup vs baseline: 1.1517x; 1.0958x over previous
//
#include <hip/hip_runtime.h>
#include <hip/hip_bf16.h>

typedef __bf16 bf16_t;
typedef __bf16 bf16x8 __attribute__((ext_vector_type(8)));
typedef __bf16 bf16x4 __attribute__((ext_vector_type(4)));
typedef float f32x4 __attribute__((ext_vector_type(4)));

#define B_ 16
#define T_ 128
#define H_ 512
#define L_ 2
#define V_ 32000
#define G_ 2048   /* 4*H */
#define M_ 2048   /* B*T */

#define BN 128
#define BK 64

__device__ __forceinline__ float sigf(float x) { return 1.f / (1.f + __expf(-x)); }
__device__ __forceinline__ float tanhf_(float x) { return 2.f / (1.f + __expf(-2.f * x)) - 1.f; }

// Gate-interleaved column permutation for the LSTM-gate GEMMs:
//   permuted col c in [0,2048): gate = (c>>4)&3, h = ((c>>6)<<4) | (c&15)
//   original gate row r = gate*H_ + h
// Within each 64-col group, cols {0,16,32,48}+r16 are gates i,f,g,o of ONE
// hidden unit h — exactly the columns one lane's acc[mi][0..3] holds in the
// 16x16x32 MFMA fragment layout, so the LSTM pointwise runs in registers.

// ---------------- mega prep kernel: 4 independent jobs by block range --------
__global__ __launch_bounds__(256) void prep(const float* __restrict__ emb,
                                            const int* __restrict__ target,
                                            const float* __restrict__ enc_h,
                                            const float* __restrict__ W_ih,
                                            const float* __restrict__ W_hh,
                                            const float* __restrict__ b_ih,
                                            const float* __restrict__ b_hh,
                                            const float* __restrict__ W_out,
                                            bf16_t* __restrict__ x,
                                            bf16_t* __restrict__ wih_b,
                                            bf16_t* __restrict__ wout_b,
                                            float* __restrict__ biasall) {
    const int blk = blockIdx.x;
    const int tid = threadIdx.x;
    if (blk < 256) {
        // ---- hproj (gate-permuted bias table) ----
        int idx = blk * 256 + tid;             // L_*G_*B_
        int b = idx & 15;
        int c = (idx >> 4) & (G_ - 1);
        int l = idx >> 15;
        int gate = (c >> 4) & 3;
        int h = ((c >> 6) << 4) | (c & 15);
        int r = gate * H_ + h;                 // original gate row
        const float* hrow = enc_h + ((size_t)l * B_ + b) * H_;
        const float* wrow = W_hh + ((size_t)l * G_ + r) * H_;
        float acc = b_ih[l * G_ + r] + b_hh[l * G_ + r];
        #pragma unroll 4
        for (int k = 0; k < H_; k += 4) {
            float4 hv = *(const float4*)(hrow + k);
            float4 wv = *(const float4*)(wrow + k);
            acc += hv.x * wv.x + hv.y * wv.y + hv.z * wv.z + hv.w * wv.w;
        }
        biasall[((size_t)l * B_ + b) * G_ + c] = acc;
    } else if (blk < 2304) {
        // ---- W_ih convert + gate-permute rows ----
        int idx = (blk - 256) * 256 + tid;     // L_*G_*(H_/4)
        int k4 = idx & 127;
        int c  = (idx >> 7) & (G_ - 1);
        int l  = idx >> 18;
        int gate = (c >> 4) & 3;
        int h = ((c >> 6) << 4) | (c & 15);
        int r = gate * H_ + h;
        float4 v = *(const float4*)(W_ih + ((size_t)l * G_ + r) * H_ + k4 * 4);
        bf16x4 o;
        o[0] = (bf16_t)v.x; o[1] = (bf16_t)v.y; o[2] = (bf16_t)v.z; o[3] = (bf16_t)v.w;
        *(bf16x4*)(wih_b + ((size_t)l * G_ + c) * H_ + k4 * 4) = o;
    } else if (blk < 3328) {
        // ---- embedding gather + relu -> bf16 ----
        int idx = (blk - 2304) * 256 + tid;    // M_*(H_/4)
        int m  = idx >> 7;
        int h4 = (idx & 127) << 2;
        int b = m >> 7, t = m & 127;
        int tok = (t == 0) ? 1 : target[b * T_ + t - 1];
        float4 v = *(const float4*)(emb + (size_t)tok * H_ + h4);
        bf16x4 o;
        o[0] = (bf16_t)fmaxf(v.x, 0.f);
        o[1] = (bf16_t)fmaxf(v.y, 0.f);
        o[2] = (bf16_t)fmaxf(v.z, 0.f);
        o[3] = (bf16_t)fmaxf(v.w, 0.f);
        *(bf16x4*)(x + (size_t)m * H_ + h4) = o;
    } else {
        // ---- W_out convert ----
        int idx = (blk - 3328) * 256 + tid;    // V_*H_/4
        float4 v = ((const float4*)W_out)[idx];
        bf16x4 o;
        o[0] = (bf16_t)v.x; o[1] = (bf16_t)v.y; o[2] = (bf16_t)v.z; o[3] = (bf16_t)v.w;
        ((bf16x4*)wout_b)[idx] = o;
    }
}

// ---------------- bf16 GEMM:  C(MxN) = A(MxK) @ B(NxK)^T  -------------------
// BK=64 (half the barrier drains of BK=32), LDS rows XOR-swizzled in 16B
// units: LDS[r][w] holds global[r][w ^ (r&7)] (linear gload_lds dest +
// pre-swizzled SOURCE, swizzled READ — both-sides rule). ds_read_b128 drops
// from 16-way to 2-way bank aliasing (free).
// MODE 0: logits epilogue, C[row*N+col] = acc + bias[col] (nontemporal).
// MODE 1: fused LSTM pointwise epilogue (gate-permuted B/bias).
template<int BMt, int MODE>
__global__ __launch_bounds__(256) void gemm_bt(const bf16_t* __restrict__ A,
                                               const bf16_t* __restrict__ B,
                                               float* __restrict__ C,
                                               const float* __restrict__ bias,
                                               int M, int N, int K,
                                               const float* __restrict__ enc_c,
                                               bf16_t* __restrict__ xout,
                                               float* __restrict__ out_h,
                                               float* __restrict__ out_c,
                                               int l) {
    constexpr int MIc = BMt / 32;        // per-wave mi count (128->4, 64->2)
    constexpr int NA  = BMt / 8;         // A staging issues (8 rows each)
    constexpr int NB  = BN / 8;          // B staging issues
    __shared__ __align__(16) bf16_t As[BMt * BK];
    __shared__ __align__(16) bf16_t Bs[BN * BK];

    const int tid  = threadIdx.x;
    const int lane = tid & 63;
    const int wave = tid >> 6;
    const int wm = wave >> 1, wn = wave & 1;
    const int quad = lane >> 4;
    const int r16  = lane & 15;

    // XCD-bijective remap (gridDim.x divisible by 8 for all our shapes)
    const int nwg = gridDim.x;
    const int q  = nwg >> 3;
    const int wg = (blockIdx.x & 7) * q + (blockIdx.x >> 3);
    const int nbx = M / BMt;
    const int bx = wg % nbx;
    const int by = wg / nbx;
    const int tileM = bx * BMt;
    const int tileN = by * BN;

    // staging: each gload_lds covers 8 rows x 128B; lane -> row lane>>3,
    // LDS 16B-unit lane&7; source unit pre-swizzled so LDS[r][w]=G[r][w^(r&7)]
    const int srow = lane >> 3;
    const int scol = (((lane & 7) ^ (lane >> 3)) << 3);   // elems

    f32x4 acc[MIc][4];
    #pragma unroll
    for (int i = 0; i < MIc; i++)
        #pragma unroll
        for (int j = 0; j < 4; j++) acc[i][j] = (f32x4){0.f, 0.f, 0.f, 0.f};

    const int nk = K / BK;
    for (int kt = 0; kt < nk; ++kt) {
        const int k0 = kt * BK;
        #pragma unroll
        for (int ii = 0; ii < (NA + NB) / 4; ++ii) {
            const int i = ii * 4 + wave;
            const bf16_t* src;
            bf16_t* dst;
            if (i < NA) {
                const int r0 = i * 8;
                src = A + (size_t)(tileM + r0 + srow) * K + k0 + scol;
                dst = As + r0 * BK;
            } else {
                const int r0 = (i - NA) * 8;
                src = B + (size_t)(tileN + r0 + srow) * K + k0 + scol;
                dst = Bs + r0 * BK;
            }
            __builtin_amdgcn_global_load_lds(
                (const __attribute__((address_space(1))) void*)src,
                (__attribute__((address_space(3))) void*)dst, 16, 0, 0);
        }
        __syncthreads();

        #pragma unroll
        for (int ks = 0; ks < 2; ++ks) {
            bf16x8 af[MIc], bfr[4];
            const int ub = ks * 4 + quad;                 // logical 16B unit
            #pragma unroll
            for (int mi = 0; mi < MIc; mi++) {
                const int row = wm * (BMt / 2) + mi * 16 + r16;
                af[mi] = *(const bf16x8*)(As + row * BK + ((ub ^ (r16 & 7)) << 3));
            }
            #pragma unroll
            for (int ni = 0; ni < 4; ni++) {
                const int row = wn * 64 + ni * 16 + r16;
                bfr[ni] = *(const bf16x8*)(Bs + row * BK + ((ub ^ (r16 & 7)) << 3));
            }
            #pragma unroll
            for (int mi = 0; mi < MIc; mi++)
                #pragma unroll
                for (int ni = 0; ni < 4; ni++)
                    acc[mi][ni] = __builtin_amdgcn_mfma_f32_16x16x32_bf16(
                        af[mi], bfr[ni], acc[mi][ni], 0, 0, 0);
        }
        __syncthreads();
    }

    if (MODE == 0) {
        // ---- logits epilogue ----
        #pragma unroll
        for (int mi = 0; mi < MIc; mi++) {
            #pragma unroll
            for (int ni = 0; ni < 4; ni++) {
                const int col = tileN + wn * 64 + ni * 16 + r16;
                const float bv = bias[col];
                #pragma unroll
                for (int rr = 0; rr < 4; rr++) {
                    const int row = tileM + wm * (BMt / 2) + mi * 16 + quad * 4 + rr;
                    __builtin_nontemporal_store(acc[mi][ni][rr] + bv,
                                                &C[(size_t)row * N + col]);
                }
            }
        }
    } else {
        // ---- fused LSTM pointwise epilogue ----
        const int b = tileM >> 7;              // block spans one batch row
        const float* brow = bias + (size_t)b * G_;
        float bv[4];
        #pragma unroll
        for (int g = 0; g < 4; g++)
            bv[g] = brow[tileN + wn * 64 + g * 16 + r16];
        const int h = (2 * by + wn) * 16 + r16;
        const float c0 = enc_c[((size_t)l * B_ + b) * H_ + h];
        #pragma unroll
        for (int mi = 0; mi < MIc; mi++) {
            #pragma unroll
            for (int rr = 0; rr < 4; rr++) {
                const int t = (tileM & 127) + wm * (BMt / 2) + mi * 16 + quad * 4 + rr;
                const float gi = acc[mi][0][rr] + bv[0];
                const float gf = acc[mi][1][rr] + bv[1];
                const float gg = acc[mi][2][rr] + bv[2];
                const float go = acc[mi][3][rr] + bv[3];
                const float c = sigf(gf) * c0 + sigf(gi) * tanhf_(gg);
                const float hv = sigf(go) * tanhf_(c);
                xout[(size_t)(b * T_ + t) * H_ + h] = (bf16_t)hv;
                if (t == T_ - 1) {
                    out_h[((size_t)l * B_ + b) * H_ + h] = hv;
                    out_c[((size_t)l * B_ + b) * H_ + h] = c;
                }
            }
        }
    }
}

extern "C" void kernel_launch(void* const* d_in, const int* in_sizes, int n_in,
                              void* d_out, int out_size, void* d_ws, size_t ws_size,
                              hipStream_t stream) {
    const float* enc_h  = (const float*)d_in[1];
    const float* enc_c  = (const float*)d_in[2];
    const int*   target = (const int*)d_in[3];
    const float* emb    = (const float*)d_in[4];
    const float* W_ih   = (const float*)d_in[5];
    const float* W_hh   = (const float*)d_in[6];
    const float* b_ih   = (const float*)d_in[7];
    const float* b_hh   = (const float*)d_in[8];
    const float* W_out  = (const float*)d_in[9];
    const float* b_out  = (const float*)d_in[10];
    float* out = (float*)d_out;

    // workspace layout (bytes)
    char* w = (char*)d_ws;
    bf16_t* x       = (bf16_t*)(w);                         // 2 MB
    bf16_t* wih_b   = (bf16_t*)(w + 2097152);               // 4 MB
    bf16_t* wout_b  = (bf16_t*)(w + 6291456);               // 32.75 MB
    bf16_t* x2      = (bf16_t*)(w + 39059456);              // 2 MB
    float*  biasall = (float*)(w + 55836672);               // 256 KB

    float* out_h = out + (size_t)M_ * V_;
    float* out_c = out_h + (size_t)L_ * B_ * H_;

    // 1) all prep in one launch
    prep<<<19328, 256, 0, stream>>>(emb, target, enc_h, W_ih, W_hh, b_ih, b_hh,
                                    W_out, x, wih_b, wout_b, biasall);

    // 2) two LSTM layers: GEMM with fused pointwise epilogue (BM=64 -> 2 blk/CU)
    gemm_bt<64, 1><<<(M_ / 64) * (G_ / BN), 256, 0, stream>>>(
        x, wih_b, nullptr, biasall, M_, G_, H_,
        enc_c, x2, out_h, out_c, 0);
    gemm_bt<64, 1><<<(M_ / 64) * (G_ / BN), 256, 0, stream>>>(
        x2, wih_b + (size_t)G_ * H_, nullptr, biasall + (size_t)B_ * G_,
        M_, G_, H_, enc_c, x, out_h, out_c, 1);

    // 3) logits = x @ W_out^T + b_out
    gemm_bt<128, 0><<<(M_ / 128) * (V_ / BN), 256, 0, stream>>>(
        x, wout_b, out, b_out, M_, V_, H_,
        nullptr, nullptr, nullptr, nullptr, 0);
}